// Round 1
// baseline (6669.364 us; speedup 1.0000x reference)
//
#include <hip/hip_runtime.h>

namespace {

constexpr int KSTEPS = 1024;
constexpr int BTOT   = 512;
constexpr size_t OFF_R = (size_t)BTOT * KSTEPS * 5;                      // rates offset
constexpr size_t OFF_D = OFF_R + (size_t)BTOT * KSTEPS * 8;              // dhid offset

__device__ __forceinline__ float sigf(float x) {
    return 1.0f / (1.0f + __expf(-x));
}
__device__ __forceinline__ float tanhfast(float x) {
    float e2 = __expf(2.0f * x);
    return 1.0f - 2.0f / (e2 + 1.0f);   // inf-safe: large x -> 1, large -x -> -1
}

// RHS of the 5-state chain: d = A(rates) * y  (flux form, matches reference exactly)
#define CHAIN_RHS(d, yy)                                   \
    {                                                      \
        float f1 = kf1 * yy[0] - kr1 * yy[1];              \
        float f2 = kf2 * yy[1] - kr2 * yy[2];              \
        float f3 = kf3 * yy[2] - kr3 * yy[3];              \
        float f4 = kf4 * yy[3] - kr4 * yy[4];              \
        d[0] = -f1;                                        \
        d[1] = f1 - f2;                                    \
        d[2] = f2 - f3;                                    \
        d[3] = f3 - f4;                                    \
        d[4] = f4;                                         \
    }

__global__ __launch_bounds__(384, 2) void rnn_fused(
    const float* __restrict__ y0,     const float* __restrict__ u_seq,
    const float* __restrict__ dt_seq, const float* __restrict__ W_lift,
    const float* __restrict__ b_lift, const float* __restrict__ W_ih,
    const float* __restrict__ W_hh,   const float* __restrict__ b_ih,
    const float* __restrict__ b_hh,   const float* __restrict__ W_head,
    const float* __restrict__ b_head, const float* __restrict__ u2y,
    float* __restrict__ out)
{
    const int t  = threadIdx.x;        // 0..383 ; thread t owns GRU output row t
    const int wg = blockIdx.x;         // 0..255
    const int b0 = wg * 2;             // two batch rows per WG

    __shared__ alignas(16) float sWlift[64 * 9];
    __shared__ float sblift[64];
    __shared__ alignas(16) float sWheadP[13 * 132];   // padded stride 132 (bank-conflict safe)
    __shared__ float sbhead[13];
    __shared__ float sU2Y[20];                        // (U=4, P=5) row-major
    __shared__ alignas(16) float sX[2][64];
    __shared__ alignas(16) float sH[2][128];
    __shared__ float sGi[2][384];
    __shared__ float sGh[2][384];
    __shared__ float sY[2][8];
    __shared__ float sRates[2][8];
    __shared__ float sDhid[2][8];
    __shared__ alignas(16) float sU[2][4];
    __shared__ float sDt[2];

    // ---- per-thread register-resident weight rows (loaded once) ----
    float wih[64];
    float whh[128];
    {
        const float4* p = (const float4*)(W_ih + (size_t)t * 64);
#pragma unroll
        for (int i = 0; i < 16; i++) {
            float4 v = p[i];
            wih[4 * i + 0] = v.x; wih[4 * i + 1] = v.y;
            wih[4 * i + 2] = v.z; wih[4 * i + 3] = v.w;
        }
        const float4* q = (const float4*)(W_hh + (size_t)t * 128);
#pragma unroll
        for (int i = 0; i < 32; i++) {
            float4 v = q[i];
            whh[4 * i + 0] = v.x; whh[4 * i + 1] = v.y;
            whh[4 * i + 2] = v.z; whh[4 * i + 3] = v.w;
        }
    }
    const float bih = b_ih[t];
    const float bhh = b_hh[t];

    // ---- cooperative LDS init ----
    for (int i = t; i < 576; i += 384) sWlift[i] = W_lift[i];
    if (t < 64) sblift[t] = b_lift[t];
    for (int i = t; i < 13 * 128; i += 384) {
        int o = i >> 7, c = i & 127;
        sWheadP[o * 132 + c] = W_head[i];
    }
    if (t < 13) sbhead[t] = b_head[t];
    if (t < 20) sU2Y[t] = u2y[t];
    if (t < 256) sH[t >> 7][t & 127] = 0.0f;
    if (t < 10) { int r = t / 5, s = t % 5; sY[r][s] = y0[(b0 + r) * 5 + s] + 0.01f; }
    sGh[0][t] = bhh;   // gh(k=0) = b_hh + W_hh @ 0 = b_hh
    sGh[1][t] = bhh;
    if (t < 8)  { int r = t >> 2, m = t & 3; sU[r][m] = u_seq[((size_t)(b0 + r) * KSTEPS + 0) * 4 + m]; }
    if (t >= 8 && t < 10) { int r = t - 8; sDt[r] = dt_seq[(size_t)(b0 + r) * KSTEPS + 0]; }
    __syncthreads();

    float4 upf = make_float4(0.f, 0.f, 0.f, 0.f);  // u prefetch (lanes 256,257)
    float  dpf = 0.f;                              // dt prefetch (lanes 258,259)

    for (int k = 0; k < KSTEPS; k++) {
        // ---------- phase A: prefetch issue + lift ----------
        if (t >= 256 && t < 260 && (k + 1) < KSTEPS) {
            if (t < 258) {
                int r = t - 256;
                upf = *(const float4*)&u_seq[((size_t)(b0 + r) * KSTEPS + (k + 1)) * 4];
            } else {
                int r = t - 258;
                dpf = dt_seq[(size_t)(b0 + r) * KSTEPS + (k + 1)];
            }
        }
        if (t < 128) {
            int r = t >> 6, l = t & 63;
            const float* wl = &sWlift[l * 9];
            float acc = sblift[l];
            acc = fmaf(wl[0], sU[r][0], acc);
            acc = fmaf(wl[1], sU[r][1], acc);
            acc = fmaf(wl[2], sU[r][2], acc);
            acc = fmaf(wl[3], sU[r][3], acc);
            acc = fmaf(wl[4], sY[r][0], acc);
            acc = fmaf(wl[5], sY[r][1], acc);
            acc = fmaf(wl[6], sY[r][2], acc);
            acc = fmaf(wl[7], sY[r][3], acc);
            acc = fmaf(wl[8], sY[r][4], acc);
            sX[r][l] = acc * sigf(acc);   // silu
        }
        __syncthreads();

        // ---------- phase B: gi = b_ih + W_ih @ x (both rows) ----------
        {
            float g0 = bih, g1 = bih;
            const float4* x0 = (const float4*)(&sX[0][0]);
            const float4* x1 = (const float4*)(&sX[1][0]);
#pragma unroll
            for (int i = 0; i < 16; i++) {
                float4 a = x0[i];
                float4 c = x1[i];
                g0 = fmaf(wih[4 * i + 0], a.x, g0);
                g0 = fmaf(wih[4 * i + 1], a.y, g0);
                g0 = fmaf(wih[4 * i + 2], a.z, g0);
                g0 = fmaf(wih[4 * i + 3], a.w, g0);
                g1 = fmaf(wih[4 * i + 0], c.x, g1);
                g1 = fmaf(wih[4 * i + 1], c.y, g1);
                g1 = fmaf(wih[4 * i + 2], c.z, g1);
                g1 = fmaf(wih[4 * i + 3], c.w, g1);
            }
            sGi[0][t] = g0;
            sGi[1][t] = g1;
        }
        __syncthreads();

        // ---------- phase C: GRU gates -> h_new ----------
        if (t < 256) {
            int r = t >> 7, q = t & 127;
            float ir = sGi[r][q],       hr = sGh[r][q];
            float iz = sGi[r][q + 128], hz = sGh[r][q + 128];
            float in_ = sGi[r][q + 256], hn = sGh[r][q + 256];
            float rr = sigf(ir + hr);
            float z  = sigf(iz + hz);
            float n  = tanhfast(fmaf(rr, hn, in_));
            float h  = sH[r][q];
            sH[r][q] = fmaf(z, h - n, n);     // (1-z)*n + z*h
        }
        __syncthreads();

        // ---------- phase D: head (lanes 0..25) ; RK4 lanes snapshot u(k)/dt(k) ----------
        float um0 = 0.f, um1 = 0.f, um2 = 0.f, um3 = 0.f, dtv = 0.f;
        if (t < 2) {
            um0 = sU[t][0]; um1 = sU[t][1]; um2 = sU[t][2]; um3 = sU[t][3];
            dtv = sDt[t];
        }
        if (t < 26) {
            int r = (t >= 13) ? 1 : 0;
            int o = t - 13 * r;
            float acc = sbhead[o];
            const float4* wv = (const float4*)(&sWheadP[o * 132]);
            const float4* hv = (const float4*)(&sH[r][0]);
#pragma unroll
            for (int i = 0; i < 32; i++) {
                float4 w = wv[i];
                float4 h4 = hv[i];
                acc = fmaf(w.x, h4.x, acc);
                acc = fmaf(w.y, h4.y, acc);
                acc = fmaf(w.z, h4.z, acc);
                acc = fmaf(w.w, h4.w, acc);
            }
            if (o < 8) {
                float rate = fmaf(2.99f, sigf(acc), 0.01f);
                sRates[r][o] = rate;
                out[OFF_R + ((size_t)(b0 + r) * KSTEPS + k) * 8 + o] = rate;
            } else {
                float dh = 3.0f * sigf(acc);
                sDhid[r][o - 8] = dh;
                out[OFF_D + ((size_t)(b0 + r) * KSTEPS + k) * 5 + (o - 8)] = dh;
            }
        }
        __syncthreads();

        // ---------- phase E: gh(k+1) (all threads) || RK4 (lanes 0,1) || u_lds update ----------
        {
            float g0 = bhh, g1 = bhh;
            const float4* h0 = (const float4*)(&sH[0][0]);
            const float4* h1 = (const float4*)(&sH[1][0]);
#pragma unroll
            for (int i = 0; i < 32; i++) {
                float4 a = h0[i];
                float4 c = h1[i];
                g0 = fmaf(whh[4 * i + 0], a.x, g0);
                g0 = fmaf(whh[4 * i + 1], a.y, g0);
                g0 = fmaf(whh[4 * i + 2], a.z, g0);
                g0 = fmaf(whh[4 * i + 3], a.w, g0);
                g1 = fmaf(whh[4 * i + 0], c.x, g1);
                g1 = fmaf(whh[4 * i + 1], c.y, g1);
                g1 = fmaf(whh[4 * i + 2], c.z, g1);
                g1 = fmaf(whh[4 * i + 3], c.w, g1);
            }
            sGh[0][t] = g0;
            sGh[1][t] = g1;
        }
        if (t >= 256 && t < 260 && (k + 1) < KSTEPS) {
            if (t < 258) {
                int r = t - 256;
                *(float4*)&sU[r][0] = upf;
            } else {
                sDt[t - 258] = dpf;
            }
        }
        if (t < 2) {
            const int r = t;
            float ya[5];
            float kf1 = sRates[r][0], kf2 = sRates[r][1], kf3 = sRates[r][2], kf4 = sRates[r][3];
            float kr1 = sRates[r][4], kr2 = sRates[r][5], kr3 = sRates[r][6], kr4 = sRates[r][7];
#pragma unroll
            for (int s = 0; s < 5; s++) {
                float jmp = um0 * sU2Y[s];
                jmp = fmaf(um1, sU2Y[5 + s], jmp);
                jmp = fmaf(um2, sU2Y[10 + s], jmp);
                jmp = fmaf(um3, sU2Y[15 + s], jmp);
                ya[s] = sY[r][s] + jmp + sDhid[r][s];
            }
            const float hs = dtv * 0.1f;       // dt / N_SUB
            const float h2 = 0.5f * hs;
            const float h6 = hs * (1.0f / 6.0f);
            for (int ss = 0; ss < 10; ss++) {
                float k1[5], k2[5], k3[5], k4[5], tp[5];
                CHAIN_RHS(k1, ya);
#pragma unroll
                for (int i = 0; i < 5; i++) tp[i] = fmaf(h2, k1[i], ya[i]);
                CHAIN_RHS(k2, tp);
#pragma unroll
                for (int i = 0; i < 5; i++) tp[i] = fmaf(h2, k2[i], ya[i]);
                CHAIN_RHS(k3, tp);
#pragma unroll
                for (int i = 0; i < 5; i++) tp[i] = fmaf(hs, k3[i], ya[i]);
                CHAIN_RHS(k4, tp);
#pragma unroll
                for (int i = 0; i < 5; i++) {
                    float sum = k1[i] + 2.0f * (k2[i] + k3[i]) + k4[i];
                    ya[i] = fmaxf(fmaf(h6, sum, ya[i]), 0.0f);
                }
            }
#pragma unroll
            for (int i = 0; i < 5; i++) {
                sY[r][i] = ya[i];
                out[((size_t)(b0 + r) * KSTEPS + k) * 5 + i] = ya[i];
            }
        }
        __syncthreads();
    }
}

}  // namespace

extern "C" void kernel_launch(void* const* d_in, const int* in_sizes, int n_in,
                              void* d_out, int out_size, void* d_ws, size_t ws_size,
                              hipStream_t stream) {
    const float* y0     = (const float*)d_in[0];
    const float* u_seq  = (const float*)d_in[1];
    const float* dt_seq = (const float*)d_in[2];
    const float* W_lift = (const float*)d_in[3];
    const float* b_lift = (const float*)d_in[4];
    const float* W_ih   = (const float*)d_in[5];
    const float* W_hh   = (const float*)d_in[6];
    const float* b_ih   = (const float*)d_in[7];
    const float* b_hh   = (const float*)d_in[8];
    const float* W_head = (const float*)d_in[9];
    const float* b_head = (const float*)d_in[10];
    const float* u2y    = (const float*)d_in[11];
    float* out = (float*)d_out;

    rnn_fused<<<256, 384, 0, stream>>>(y0, u_seq, dt_seq, W_lift, b_lift,
                                       W_ih, W_hh, b_ih, b_hh, W_head, b_head,
                                       u2y, out);
}

// Round 2
// 4801.818 us; speedup vs baseline: 1.3889x; 1.3889x over previous
//
#include <hip/hip_runtime.h>

namespace {

constexpr int KSTEPS = 1024;
constexpr int BTOT   = 512;
constexpr size_t OFF_R = (size_t)BTOT * KSTEPS * 5;                      // rates offset
constexpr size_t OFF_D = OFF_R + (size_t)BTOT * KSTEPS * 8;              // dhid offset

__device__ __forceinline__ float sigf(float x) {
    return 1.0f / (1.0f + __expf(-x));
}
__device__ __forceinline__ float tanhfast(float x) {
    float e2 = __expf(2.0f * x);
    return 1.0f - 2.0f / (e2 + 1.0f);   // inf-safe
}

// RHS of the 5-state chain (flux form, matches reference exactly)
#define CHAIN_RHS(d, yy)                                   \
    {                                                      \
        float f1 = kf1 * yy[0] - kr1 * yy[1];              \
        float f2 = kf2 * yy[1] - kr2 * yy[2];              \
        float f3 = kf3 * yy[2] - kr3 * yy[3];              \
        float f4 = kf4 * yy[3] - kr4 * yy[4];              \
        d[0] = -f1;                                        \
        d[1] = f1 - f2;                                    \
        d[2] = f2 - f3;                                    \
        d[3] = f3 - f4;                                    \
        d[4] = f4;                                         \
    }

__global__ __launch_bounds__(768, 3) void rnn_fused(
    const float* __restrict__ y0,     const float* __restrict__ u_seq,
    const float* __restrict__ dt_seq, const float* __restrict__ W_lift,
    const float* __restrict__ b_lift, const float* __restrict__ W_ih,
    const float* __restrict__ W_hh,   const float* __restrict__ b_ih,
    const float* __restrict__ b_hh,   const float* __restrict__ W_head,
    const float* __restrict__ b_head, const float* __restrict__ u2y,
    float* __restrict__ out)
{
    const int t  = threadIdx.x;          // 0..767
    const int hf = (t >= 384) ? 1 : 0;   // column half (wave-uniform: waves 0-5 / 6-11)
    const int o  = t - hf * 384;         // owned GRU output row 0..383
    const int wg = blockIdx.x;
    const int b0 = wg * 2;               // two batch rows per WG

    __shared__ alignas(16) float sWlift[64 * 9];
    __shared__ float sblift[64];
    __shared__ alignas(16) float sWheadP[13 * 132];   // padded stride 132
    __shared__ float sbhead[16];
    __shared__ float sU2Y[20];
    __shared__ alignas(16) float sX[2][64];
    __shared__ alignas(16) float sH[2][128];
    __shared__ float sGiP[2][2][384];     // [half][row][out]
    __shared__ float sGhP[2][2][384];
    __shared__ float sY[2][8];
    __shared__ float sRates[2][8];
    __shared__ float sDhid[2][8];
    __shared__ alignas(16) float sU[2][4];
    __shared__ float sDt[2];

    // ---- per-thread register-resident half weight rows (96 floats) ----
    float wih[32];
    float whh[64];
    {
        const float4* p = (const float4*)(W_ih + (size_t)o * 64 + hf * 32);
#pragma unroll
        for (int i = 0; i < 8; i++) {
            float4 v = p[i];
            wih[4 * i + 0] = v.x; wih[4 * i + 1] = v.y;
            wih[4 * i + 2] = v.z; wih[4 * i + 3] = v.w;
        }
        const float4* q = (const float4*)(W_hh + (size_t)o * 128 + hf * 64);
#pragma unroll
        for (int i = 0; i < 16; i++) {
            float4 v = q[i];
            whh[4 * i + 0] = v.x; whh[4 * i + 1] = v.y;
            whh[4 * i + 2] = v.z; whh[4 * i + 3] = v.w;
        }
    }
    const float bihv = hf ? 0.0f : b_ih[o];
    const float bhhv = hf ? 0.0f : b_hh[o];

    // ---- cooperative LDS init ----
    for (int i = t; i < 576; i += 768) sWlift[i] = W_lift[i];
    if (t < 64) sblift[t] = b_lift[t];
    for (int i = t; i < 13 * 128; i += 768) {
        int oo = i >> 7, c = i & 127;
        sWheadP[oo * 132 + c] = W_head[i];
    }
    if (t < 13) sbhead[t] = b_head[t];
    if (t < 20) sU2Y[t] = u2y[t];
    if (t < 256) sH[t >> 7][t & 127] = 0.0f;
    if (t < 10) { int r = t / 5, s = t % 5; sY[r][s] = y0[(b0 + r) * 5 + s] + 0.01f; }
    // gh(k=0) partials: h0 = 0 -> gh = b_hh (half 0 carries the bias)
    sGhP[hf][0][o] = bhhv;
    sGhP[hf][1][o] = bhhv;
    if (t < 8)  { int r = t >> 2, m = t & 3; sU[r][m] = u_seq[((size_t)(b0 + r) * KSTEPS + 0) * 4 + m]; }
    if (t >= 8 && t < 10) { int r = t - 8; sDt[r] = dt_seq[(size_t)(b0 + r) * KSTEPS + 0]; }
    __syncthreads();

    float4 upf = make_float4(0.f, 0.f, 0.f, 0.f);  // u prefetch (lanes 256,257)
    float  dpf = 0.f;                              // dt prefetch (lanes 258,259)

    for (int k = 0; k < KSTEPS; k++) {
        // ---------- phase A: prefetch issue + lift ----------
        if (t >= 256 && t < 260 && (k + 1) < KSTEPS) {
            if (t < 258) {
                int r = t - 256;
                upf = *(const float4*)&u_seq[((size_t)(b0 + r) * KSTEPS + (k + 1)) * 4];
            } else {
                int r = t - 258;
                dpf = dt_seq[(size_t)(b0 + r) * KSTEPS + (k + 1)];
            }
        }
        if (t < 128) {
            int r = t >> 6, l = t & 63;
            const float* wl = &sWlift[l * 9];
            float acc = sblift[l];
            acc = fmaf(wl[0], sU[r][0], acc);
            acc = fmaf(wl[1], sU[r][1], acc);
            acc = fmaf(wl[2], sU[r][2], acc);
            acc = fmaf(wl[3], sU[r][3], acc);
            acc = fmaf(wl[4], sY[r][0], acc);
            acc = fmaf(wl[5], sY[r][1], acc);
            acc = fmaf(wl[6], sY[r][2], acc);
            acc = fmaf(wl[7], sY[r][3], acc);
            acc = fmaf(wl[8], sY[r][4], acc);
            sX[r][l] = acc * sigf(acc);   // silu
        }
        __syncthreads();

        // ---------- phase B: gi half-partials (all 768 threads) ----------
        {
            float g0 = bihv, g1 = 0.0f;
            const float4* x0 = (const float4*)(&sX[0][hf * 32]);
            const float4* x1 = (const float4*)(&sX[1][hf * 32]);
#pragma unroll
            for (int i = 0; i < 8; i++) {
                float4 a = x0[i];
                float4 c = x1[i];
                g0 = fmaf(wih[4 * i + 0], a.x, g0);
                g0 = fmaf(wih[4 * i + 1], a.y, g0);
                g0 = fmaf(wih[4 * i + 2], a.z, g0);
                g0 = fmaf(wih[4 * i + 3], a.w, g0);
                g1 = fmaf(wih[4 * i + 0], c.x, g1);
                g1 = fmaf(wih[4 * i + 1], c.y, g1);
                g1 = fmaf(wih[4 * i + 2], c.z, g1);
                g1 = fmaf(wih[4 * i + 3], c.w, g1);
            }
            sGiP[hf][0][o] = g0;
            sGiP[hf][1][o] = g1;
        }
        __syncthreads();

        // ---------- phase C: GRU gates -> h_new ----------
        if (t < 256) {
            int r = t >> 7, q = t & 127;
            float ir  = sGiP[0][r][q]       + sGiP[1][r][q];
            float iz  = sGiP[0][r][q + 128] + sGiP[1][r][q + 128];
            float in_ = sGiP[0][r][q + 256] + sGiP[1][r][q + 256];
            float hr  = sGhP[0][r][q]       + sGhP[1][r][q];
            float hz  = sGhP[0][r][q + 128] + sGhP[1][r][q + 128];
            float hn  = sGhP[0][r][q + 256] + sGhP[1][r][q + 256];
            float rr = sigf(ir + hr);
            float z  = sigf(iz + hz);
            float n  = tanhfast(fmaf(rr, hn, in_));
            float h  = sH[r][q];
            sH[r][q] = fmaf(z, h - n, n);     // (1-z)*n + z*h
        }
        __syncthreads();

        // ---------- phase D: head, 8 lanes per output ----------
        float um0 = 0.f, um1 = 0.f, um2 = 0.f, um3 = 0.f, dtv = 0.f;
        if (t < 2) {   // RK4 lanes snapshot u(k)/dt(k)
            um0 = sU[t][0]; um1 = sU[t][1]; um2 = sU[t][2]; um3 = sU[t][3];
            dtv = sDt[t];
        }
        if (t < 208) {
            int og = t >> 3, sub = t & 7;           // output group 0..25, sub-lane 0..7
            int r  = (og >= 13) ? 1 : 0;
            int oo = og - 13 * r;
            const float4* wv = (const float4*)(&sWheadP[oo * 132 + sub * 16]);
            const float4* hv = (const float4*)(&sH[r][sub * 16]);
            float4 w0 = wv[0], w1 = wv[1], w2 = wv[2], w3 = wv[3];
            float4 h0 = hv[0], h1 = hv[1], h2 = hv[2], h3 = hv[3];
            float a0 = w0.x * h0.x, a1 = w2.x * h2.x;
            a0 = fmaf(w0.y, h0.y, a0); a1 = fmaf(w2.y, h2.y, a1);
            a0 = fmaf(w0.z, h0.z, a0); a1 = fmaf(w2.z, h2.z, a1);
            a0 = fmaf(w0.w, h0.w, a0); a1 = fmaf(w2.w, h2.w, a1);
            a0 = fmaf(w1.x, h1.x, a0); a1 = fmaf(w3.x, h3.x, a1);
            a0 = fmaf(w1.y, h1.y, a0); a1 = fmaf(w3.y, h3.y, a1);
            a0 = fmaf(w1.z, h1.z, a0); a1 = fmaf(w3.z, h3.z, a1);
            a0 = fmaf(w1.w, h1.w, a0); a1 = fmaf(w3.w, h3.w, a1);
            float acc = a0 + a1;
            acc += __shfl_xor(acc, 1);
            acc += __shfl_xor(acc, 2);
            acc += __shfl_xor(acc, 4);
            if (sub == 0) {
                acc += sbhead[oo];
                if (oo < 8) {
                    float rate = fmaf(2.99f, sigf(acc), 0.01f);
                    sRates[r][oo] = rate;
                    out[OFF_R + ((size_t)(b0 + r) * KSTEPS + k) * 8 + oo] = rate;
                } else {
                    float dh = 3.0f * sigf(acc);
                    sDhid[r][oo - 8] = dh;
                    out[OFF_D + ((size_t)(b0 + r) * KSTEPS + k) * 5 + (oo - 8)] = dh;
                }
            }
        }
        __syncthreads();

        // ---------- phase E: gh(k+1) partials (all) || u commit || RK4 (lanes 0,1) ----------
        {
            float g0 = bhhv, g1 = 0.0f;
            const float4* h0 = (const float4*)(&sH[0][hf * 64]);
            const float4* h1 = (const float4*)(&sH[1][hf * 64]);
#pragma unroll
            for (int i = 0; i < 16; i++) {
                float4 a = h0[i];
                float4 c = h1[i];
                g0 = fmaf(whh[4 * i + 0], a.x, g0);
                g0 = fmaf(whh[4 * i + 1], a.y, g0);
                g0 = fmaf(whh[4 * i + 2], a.z, g0);
                g0 = fmaf(whh[4 * i + 3], a.w, g0);
                g1 = fmaf(whh[4 * i + 0], c.x, g1);
                g1 = fmaf(whh[4 * i + 1], c.y, g1);
                g1 = fmaf(whh[4 * i + 2], c.z, g1);
                g1 = fmaf(whh[4 * i + 3], c.w, g1);
            }
            sGhP[hf][0][o] = g0;
            sGhP[hf][1][o] = g1;
        }
        if (t >= 256 && t < 260 && (k + 1) < KSTEPS) {
            if (t < 258) {
                int r = t - 256;
                *(float4*)&sU[r][0] = upf;
            } else {
                sDt[t - 258] = dpf;
            }
        }
        if (t < 2) {
            const int r = t;
            float ya[5];
            float kf1 = sRates[r][0], kf2 = sRates[r][1], kf3 = sRates[r][2], kf4 = sRates[r][3];
            float kr1 = sRates[r][4], kr2 = sRates[r][5], kr3 = sRates[r][6], kr4 = sRates[r][7];
#pragma unroll
            for (int s = 0; s < 5; s++) {
                float jmp = um0 * sU2Y[s];
                jmp = fmaf(um1, sU2Y[5 + s], jmp);
                jmp = fmaf(um2, sU2Y[10 + s], jmp);
                jmp = fmaf(um3, sU2Y[15 + s], jmp);
                ya[s] = sY[r][s] + jmp + sDhid[r][s];
            }
            const float hs = dtv * 0.1f;       // dt / N_SUB
            const float h2 = 0.5f * hs;
            const float h6 = hs * (1.0f / 6.0f);
            for (int ss = 0; ss < 10; ss++) {
                float k1[5], k2[5], k3[5], k4[5], tp[5];
                CHAIN_RHS(k1, ya);
#pragma unroll
                for (int i = 0; i < 5; i++) tp[i] = fmaf(h2, k1[i], ya[i]);
                CHAIN_RHS(k2, tp);
#pragma unroll
                for (int i = 0; i < 5; i++) tp[i] = fmaf(h2, k2[i], ya[i]);
                CHAIN_RHS(k3, tp);
#pragma unroll
                for (int i = 0; i < 5; i++) tp[i] = fmaf(hs, k3[i], ya[i]);
                CHAIN_RHS(k4, tp);
#pragma unroll
                for (int i = 0; i < 5; i++) {
                    float sum = k1[i] + 2.0f * (k2[i] + k3[i]) + k4[i];
                    ya[i] = fmaxf(fmaf(h6, sum, ya[i]), 0.0f);
                }
            }
#pragma unroll
            for (int i = 0; i < 5; i++) {
                sY[r][i] = ya[i];
                out[((size_t)(b0 + r) * KSTEPS + k) * 5 + i] = ya[i];
            }
        }
        __syncthreads();
    }
}

}  // namespace

extern "C" void kernel_launch(void* const* d_in, const int* in_sizes, int n_in,
                              void* d_out, int out_size, void* d_ws, size_t ws_size,
                              hipStream_t stream) {
    const float* y0     = (const float*)d_in[0];
    const float* u_seq  = (const float*)d_in[1];
    const float* dt_seq = (const float*)d_in[2];
    const float* W_lift = (const float*)d_in[3];
    const float* b_lift = (const float*)d_in[4];
    const float* W_ih   = (const float*)d_in[5];
    const float* W_hh   = (const float*)d_in[6];
    const float* b_ih   = (const float*)d_in[7];
    const float* b_hh   = (const float*)d_in[8];
    const float* W_head = (const float*)d_in[9];
    const float* b_head = (const float*)d_in[10];
    const float* u2y    = (const float*)d_in[11];
    float* out = (float*)d_out;

    rnn_fused<<<256, 768, 0, stream>>>(y0, u_seq, dt_seq, W_lift, b_lift,
                                       W_ih, W_hh, b_ih, b_hh, W_head, b_head,
                                       u2y, out);
}